// Round 6
// baseline (81.452 us; speedup 1.0000x reference)
//
#include <hip/hip_runtime.h>

// ThinPlateSpline: out = K_query @ rbf_weights + P_query @ poly_coeffs
//   K_ij = r*ln(r), r = ||u_i - c_j|| (d=3)
//   kk = sqrt(r2) * log2(r2) * C, C = 0.5*ln2 folded into staged weights.
//
// R19: LDS is the hidden CU-SHARED serial resource. VALU/trans are
// per-SIMD (x4/CU) but the LDS unit is one per CU at ~12cyc per
// ds_read_b128 (m134). R13/R18: 4 reads x 1024 wave-j-iters/CU = ~49Kcyc
// = 20.5us/CU of LDS occupancy > VALU (9.4us/SIMD) > trans (6.8us/SIMD)
// -> explains the 33-40us plateau and why moving math between pipes
// (R14/R15) was null. Fix: amortize reads over more work per read.
//   - QPT 4 -> 8 (scalar; R17 A/B showed packed v2f = scalar), QPB=512
//   - un-duplicated records: 2 ds_read_b128 per j
//   - LDS traffic/CU: 49K -> ~12Kcyc (~5us)
//   - grid (32,32) = 1024 blocks = exactly 4/CU; VGPR ~80-100 -> 16
//     waves/CU cap (launch_bounds(256,4)) -- accepted trade
//   - LDS: 4KB staging UNION 24.6KB s_red (R18's union kept)
// New floor ~= max(VALU 8.5, trans 6.8, LDS 5.1) ~= 10-13us.
// Predicted kernel 20-26us, bench ~66-73us, LDS_Block_Size ~25KB,
// VGPR ~80-100, absmax 0.125. Pre-commit: if bench >= ~78 again, this
// lever is null too -> SGPR-batch prefetch or accept floor.

typedef float v4f __attribute__((ext_vector_type(4)));

#define BLK 256
#define NS 4              // waves per block = in-block n-splits
#define QPT 8             // queries per lane (scalar)
#define QPB (64 * QPT)    // queries per block = 512
#define JCHUNK 128        // j per block
#define JW (JCHUNK / NS)  // 32 j per wave

union SmemT {
    struct {
        v4f a[JCHUNK];   // {-2cx,-2cy,-2cz,c2}
        v4f b[JCHUNK];   // {Cwx,Cwy,Cwz,0}
    } st;                       // 4 KB, live during main loop only
    float red[NS][QPB * 3];     // 24.6 KB, live during epilogue only
};

__global__ __launch_bounds__(BLK, 4) void tps_kernel(
    const float* __restrict__ u,     // (batch, 3)
    const float* __restrict__ cp,    // (n, 3)
    const float* __restrict__ w,     // (n, 3)
    const float* __restrict__ poly,  // (4, 3)
    float* __restrict__ out,         // (batch, 3)
    int batch, int n)
{
    __shared__ SmemT sm;

    const float C = 0.34657359027997264f;  // 0.5 * ln(2)

    const int tid = threadIdx.x;
    const int j0 = blockIdx.y * JCHUNK;

    if (tid < JCHUNK) {  // stage + transform this 128-j slice
        const int g = j0 + tid;
        const float cx = cp[g * 3 + 0], cy = cp[g * 3 + 1], cz = cp[g * 3 + 2];
        sm.st.a[tid] = (v4f){-2.f * cx, -2.f * cy, -2.f * cz,
                             fmaf(cx, cx, fmaf(cy, cy, cz * cz))};
        sm.st.b[tid] = (v4f){C * w[g * 3 + 0], C * w[g * 3 + 1],
                             C * w[g * 3 + 2], 0.f};
    }
    __syncthreads();

    const int lane = tid & 63;
    const int wv   = tid >> 6;    // 0..3 = n-split
    const int q0   = blockIdx.x * QPB + lane;   // queries q0 + k*64

    float ux[QPT], uy[QPT], uz[QPT], us[QPT];
    float ax[QPT], ay[QPT], az[QPT];
#pragma unroll
    for (int k = 0; k < QPT; ++k) {
        const int q = q0 + k * 64;
        ux[k] = u[q * 3 + 0];
        uy[k] = u[q * 3 + 1];
        uz[k] = u[q * 3 + 2];
        us[k] = fmaf(ux[k], ux[k], fmaf(uy[k], uy[k], uz[k] * uz[k]));
        ax[k] = 0.f; ay[k] = 0.f; az[k] = 0.f;
    }

    if (blockIdx.y == 0 && wv == 0) {  // polynomial term exactly once
#pragma unroll
        for (int k = 0; k < QPT; ++k) {
            ax[k] = poly[0] + ux[k] * poly[3] + uy[k] * poly[6] + uz[k] * poly[9];
            ay[k] = poly[1] + ux[k] * poly[4] + uy[k] * poly[7] + uz[k] * poly[10];
            az[k] = poly[2] + ux[k] * poly[5] + uy[k] * poly[8] + uz[k] * poly[11];
        }
    }

    const int jlo = wv * JW;
#pragma unroll 2
    for (int j = jlo; j < jlo + JW; ++j) {
        const v4f A = sm.st.a[j];   // broadcast ds_read_b128
        const v4f B = sm.st.b[j];   // broadcast ds_read_b128
#pragma unroll
        for (int k = 0; k < QPT; ++k) {
            float r2 = fmaf(A.x, ux[k],
                       fmaf(A.y, uy[k],
                       fmaf(A.z, uz[k], A.w + us[k])));
            r2 = fmaxf(r2, 1e-30f);
            const float sq = __builtin_amdgcn_sqrtf(r2);   // trans pipe
            const float lg = __builtin_amdgcn_logf(r2);    // trans pipe
            const float kk = sq * lg;                      // *C in B
            ax[k] = fmaf(kk, B.x, ax[k]);
            ay[k] = fmaf(kk, B.y, ay[k]);
            az[k] = fmaf(kk, B.z, az[k]);
        }
    }

    // Staging dead from here; re-use LDS as s_red.
    __syncthreads();   // all waves done reading sm.st

    // In-block reduction across the 4 n-split waves.
#pragma unroll
    for (int k = 0; k < QPT; ++k) {
        const int b = (k * 64 + lane) * 3;
        sm.red[wv][b + 0] = ax[k];
        sm.red[wv][b + 1] = ay[k];
        sm.red[wv][b + 2] = az[k];
    }
    __syncthreads();

    for (int v = tid; v < QPB * 3; v += BLK) {
        float s = sm.red[0][v] + sm.red[1][v] + sm.red[2][v] + sm.red[3][v];
        atomicAdd(&out[(size_t)blockIdx.x * (QPB * 3) + v], s);
    }
}

extern "C" void kernel_launch(void* const* d_in, const int* in_sizes, int n_in,
                              void* d_out, int out_size, void* d_ws, size_t ws_size,
                              hipStream_t stream) {
    const float* u    = (const float*)d_in[0];  // (batch,3)
    const float* cp   = (const float*)d_in[1];  // (n,3)
    const float* w    = (const float*)d_in[2];  // (n,3)
    const float* poly = (const float*)d_in[3];  // (4,3)
    float* out = (float*)d_out;

    const int batch = in_sizes[0] / 3;  // 16384
    const int n     = in_sizes[1] / 3;  // 4096

    hipMemsetAsync(d_out, 0, (size_t)out_size * sizeof(float), stream);

    dim3 block(BLK);
    dim3 grid(batch / QPB, n / JCHUNK);  // (32, 32) = 1024 blocks = 4/CU
    tps_kernel<<<grid, block, 0, stream>>>(u, cp, w, poly, out, batch, n);
}

// Round 7
// 79.642 us; speedup vs baseline: 1.0227x; 1.0227x over previous
//
#include <hip/hip_runtime.h>

// ThinPlateSpline: out = K_query @ rbf_weights + P_query @ poly_coeffs
//   K_ij = r*ln(r), r = ||u_i - c_j|| (d=3)
//   kk = sqrt(r2) * log2(r2) * C, C = 0.5*ln2 folded into staged weights.
//
// R20: closing resubmission of the best-measured configuration (R13,
// 78.9us bench). Session findings (R14-R19, six structural nulls):
//   - Trans ops BLOCK SIMD issue (issue-sum law: R13~R15 despite R15
//     halving trans count). Best spelling minimizes VALU*2 + trans*16;
//     hw sqrt + hw log (this kernel) is that minimum (~50 cyc static).
//   - Fitted trans cost ~30 cyc/wave64 => measured 33us kernel IS the
//     issue floor; occupancy/LDS/QPT/packed-vs-scalar levers all null.
//   - gfx950 packed fp32 = scalar fp32 throughput (fp32 peak is unpacked);
//     v2f here is codegen-neutral, kept as measured-best form.
//   - Remaining bench time = harness 256MiB poison fill (41us, serial in
//     the captured stream, not removable from kernel_launch).
// Bench floor ~= 41 (fill) + 33 (kernel) + ~4 (memset+launch) ~= 78us.

typedef float v2f __attribute__((ext_vector_type(2)));
typedef float v4f __attribute__((ext_vector_type(4)));

#define BLK 256
#define NS 4            // waves per block = in-block n-splits
#define QPT 4           // queries per lane = 2 packed groups
#define QPB 256         // queries per block = 64 * QPT
#define JCHUNK 128      // j per block
#define JW (JCHUNK / NS)

__global__ __launch_bounds__(BLK, 8) void tps_kernel(
    const float* __restrict__ u,     // (batch, 3)
    const float* __restrict__ cp,    // (n, 3)
    const float* __restrict__ w,     // (n, 3)
    const float* __restrict__ poly,  // (4, 3)
    float* __restrict__ out,         // (batch, 3)
    int batch, int n)
{
    // Pre-duplicated packed records, 2 x v4f per j each:
    //   s_a4[2j]   = {-2cx,-2cx,-2cy,-2cy}   s_a4[2j+1] = {-2cz,-2cz,c2,c2}
    //   s_b4[2j]   = {Cwx,Cwx,Cwy,Cwy}       s_b4[2j+1] = {Cwz,Cwz,0,0}
    __shared__ v4f s_a4[JCHUNK * 2];
    __shared__ v4f s_b4[JCHUNK * 2];
    __shared__ float s_red[NS][QPB * 3];   // per-wave partials (12 KB)

    const float C = 0.34657359027997264f;  // 0.5 * ln(2)

    const int tid = threadIdx.x;
    const int j0 = blockIdx.y * JCHUNK;

    if (tid < JCHUNK) {  // stage + transform + duplicate this 128-j slice
        const int g = j0 + tid;
        const float cx = cp[g * 3 + 0], cy = cp[g * 3 + 1], cz = cp[g * 3 + 2];
        const float c2 = fmaf(cx, cx, fmaf(cy, cy, cz * cz));
        const float wx = C * w[g * 3 + 0];
        const float wy = C * w[g * 3 + 1];
        const float wz = C * w[g * 3 + 2];
        s_a4[tid * 2 + 0] = (v4f){-2.f * cx, -2.f * cx, -2.f * cy, -2.f * cy};
        s_a4[tid * 2 + 1] = (v4f){-2.f * cz, -2.f * cz, c2, c2};
        s_b4[tid * 2 + 0] = (v4f){wx, wx, wy, wy};
        s_b4[tid * 2 + 1] = (v4f){wz, wz, 0.f, 0.f};
    }
    __syncthreads();

    const int lane = tid & 63;
    const int wv   = tid >> 6;    // 0..3 = n-split

    // 2 packed groups: group g holds queries (2g)*64+lane and (2g+1)*64+lane
    v2f uxv[2], uyv[2], uzv[2], usqv[2];
    v2f axv[2], ayv[2], azv[2];
#pragma unroll
    for (int g = 0; g < 2; ++g) {
        const int qa = blockIdx.x * QPB + (2 * g + 0) * 64 + lane;
        const int qb = blockIdx.x * QPB + (2 * g + 1) * 64 + lane;
        uxv[g] = (v2f){u[qa * 3 + 0], u[qb * 3 + 0]};
        uyv[g] = (v2f){u[qa * 3 + 1], u[qb * 3 + 1]};
        uzv[g] = (v2f){u[qa * 3 + 2], u[qb * 3 + 2]};
        usqv[g] = __builtin_elementwise_fma(uxv[g], uxv[g],
                  __builtin_elementwise_fma(uyv[g], uyv[g], uzv[g] * uzv[g]));
        axv[g] = (v2f){0.f, 0.f};
        ayv[g] = (v2f){0.f, 0.f};
        azv[g] = (v2f){0.f, 0.f};
    }

    if (blockIdx.y == 0 && wv == 0) {  // polynomial term exactly once
#pragma unroll
        for (int g = 0; g < 2; ++g) {
            axv[g] = poly[0] + uxv[g] * poly[3] + uyv[g] * poly[6] + uzv[g] * poly[9];
            ayv[g] = poly[1] + uxv[g] * poly[4] + uyv[g] * poly[7] + uzv[g] * poly[10];
            azv[g] = poly[2] + uxv[g] * poly[5] + uyv[g] * poly[8] + uzv[g] * poly[11];
        }
    }

    const int jlo = wv * JW;
#pragma unroll 2
    for (int j = jlo; j < jlo + JW; ++j) {
        const v4f A0 = s_a4[j * 2 + 0];  // {ax,ax,ay,ay}
        const v4f A1 = s_a4[j * 2 + 1];  // {az,az,c2,c2}
        const v4f B0 = s_b4[j * 2 + 0];  // {wx,wx,wy,wy}
        const v4f B1 = s_b4[j * 2 + 1];  // {wz,wz,0,0}
        const v2f m2x = A0.xy, m2y = A0.zw, m2z = A1.xy, c2v = A1.zw;
        const v2f wxv = B0.xy, wyv = B0.zw, wzv = B1.xy;
#pragma unroll
        for (int g = 0; g < 2; ++g) {
            v2f r2 = __builtin_elementwise_fma(m2x, uxv[g],
                     __builtin_elementwise_fma(m2y, uyv[g],
                     __builtin_elementwise_fma(m2z, uzv[g], c2v + usqv[g])));
            r2 = __builtin_elementwise_max(r2, (v2f){1e-30f, 1e-30f});
            // scalar hw trans per element (elementwise floor: 2 per pair)
            const v2f sq = {__builtin_amdgcn_sqrtf(r2.x),
                            __builtin_amdgcn_sqrtf(r2.y)};
            const v2f lg = {__builtin_amdgcn_logf(r2.x),
                            __builtin_amdgcn_logf(r2.y)};
            const v2f kk = sq * lg;      // v_pk_mul_f32
            axv[g] = __builtin_elementwise_fma(kk, wxv, axv[g]);
            ayv[g] = __builtin_elementwise_fma(kk, wyv, ayv[g]);
            azv[g] = __builtin_elementwise_fma(kk, wzv, azv[g]);
        }
    }

    // In-block reduction across the 4 n-split waves.
#pragma unroll
    for (int g = 0; g < 2; ++g) {
        const int ba = ((2 * g + 0) * 64 + lane) * 3;
        const int bb = ((2 * g + 1) * 64 + lane) * 3;
        s_red[wv][ba + 0] = axv[g].x;  s_red[wv][bb + 0] = axv[g].y;
        s_red[wv][ba + 1] = ayv[g].x;  s_red[wv][bb + 1] = ayv[g].y;
        s_red[wv][ba + 2] = azv[g].x;  s_red[wv][bb + 2] = azv[g].y;
    }
    __syncthreads();

    for (int v = tid; v < QPB * 3; v += BLK) {
        float s = s_red[0][v] + s_red[1][v] + s_red[2][v] + s_red[3][v];
        atomicAdd(&out[(size_t)blockIdx.x * (QPB * 3) + v], s);
    }
}

extern "C" void kernel_launch(void* const* d_in, const int* in_sizes, int n_in,
                              void* d_out, int out_size, void* d_ws, size_t ws_size,
                              hipStream_t stream) {
    const float* u    = (const float*)d_in[0];  // (batch,3)
    const float* cp   = (const float*)d_in[1];  // (n,3)
    const float* w    = (const float*)d_in[2];  // (n,3)
    const float* poly = (const float*)d_in[3];  // (4,3)
    float* out = (float*)d_out;

    const int batch = in_sizes[0] / 3;  // 16384
    const int n     = in_sizes[1] / 3;  // 4096

    hipMemsetAsync(d_out, 0, (size_t)out_size * sizeof(float), stream);

    dim3 block(BLK);
    dim3 grid(batch / QPB, n / JCHUNK);  // (64, 32) = 2048 blocks
    tps_kernel<<<grid, block, 0, stream>>>(u, cp, w, poly, out, batch, n);
}